// Round 9
// baseline (7318.179 us; speedup 1.0000x reference)
//
#include <hip/hip_runtime.h>
#include <hip/hip_fp16.h>

#define FD 128          // feature dim
#define NCHUNK 4        // feature chunks (32 features each; 3.2 MB fp16 -> fits 4MB XCD L2)
#define CF 32           // features per chunk
#define GRAB 16         // rows per steal-grab (4 waves x 4 rows/wave)
#define GRID_STEP 2048  // blocks for step kernels (8/CU)
#define BT 256

// ---------------- XCD identity ----------------
__device__ __forceinline__ int xcc_id() {
  int x;
  asm volatile("s_getreg_b32 %0, hwreg(HW_REG_XCC_ID)" : "=s"(x));
  return x & 7;
}

// ---------------- CSR build ----------------

__global__ void zero_i32(int* __restrict__ p, int n) {
  int i = blockIdx.x * blockDim.x + threadIdx.x;
  if (i < n) p[i] = 0;
}

__global__ void hist_kernel(const int* __restrict__ rows, int* __restrict__ cnt, int nnz) {
  int i = blockIdx.x * blockDim.x + threadIdx.x;
  if (i < nnz) atomicAdd(&cnt[rows[i]], 1);
}

__global__ void block_reduce(const int* __restrict__ cnt, int* __restrict__ bsum, int n) {
  __shared__ int sm[256];
  int i = blockIdx.x * 256 + threadIdx.x;
  sm[threadIdx.x] = (i < n) ? cnt[i] : 0;
  __syncthreads();
  for (int off = 128; off > 0; off >>= 1) {
    if (threadIdx.x < off) sm[threadIdx.x] += sm[threadIdx.x + off];
    __syncthreads();
  }
  if (threadIdx.x == 0) bsum[blockIdx.x] = sm[0];
}

__global__ void scan_bsum(const int* __restrict__ bsum, int* __restrict__ bpre, int nb) {
  __shared__ int sm[1024];
  const int tid = threadIdx.x;
  sm[tid] = (tid < nb) ? bsum[tid] : 0;
  __syncthreads();
  for (int off = 1; off < 1024; off <<= 1) {
    int t = (tid >= off) ? sm[tid - off] : 0;
    __syncthreads();
    sm[tid] += t;
    __syncthreads();
  }
  if (tid < nb) bpre[tid] = (tid == 0) ? 0 : sm[tid - 1];
}

__global__ void block_scan(const int* __restrict__ cnt, const int* __restrict__ bpre,
                           int* __restrict__ row_ptr, int n) {
  __shared__ int sm[256];
  const int tid = threadIdx.x;
  int i = blockIdx.x * 256 + tid;
  sm[tid] = (i < n) ? cnt[i] : 0;
  __syncthreads();
  for (int off = 1; off < 256; off <<= 1) {
    int t = (tid >= off) ? sm[tid - off] : 0;
    __syncthreads();
    sm[tid] += t;
    __syncthreads();
  }
  if (i < n) row_ptr[i + 1] = sm[tid] + bpre[blockIdx.x];
  if (i == 0) row_ptr[0] = 0;
}

__global__ void copy_i32(const int* __restrict__ src, int* __restrict__ dst, int n) {
  int i = blockIdx.x * blockDim.x + threadIdx.x;
  if (i < n) dst[i] = src[i];
}

// packed edge scatter: one 8B store per edge + 32-entry zero pad
__global__ void scatter_kernel(const int* __restrict__ rows, const int* __restrict__ cols,
                               const float* __restrict__ vals, int* __restrict__ fill,
                               int2* __restrict__ pk, int nnz) {
  int i = blockIdx.x * blockDim.x + threadIdx.x;
  if (i < 32) pk[nnz + i] = make_int2(0, 0);
  if (i < nnz) {
    int r = rows[i];
    int pos = atomicAdd(&fill[r], 1);
    pk[pos] = make_int2(cols[i], __float_as_int(vals[i]));
  }
}

// X (f32, [n][128]) -> Xh chunked (f16, [4][n][32])
__global__ void f32_to_f16_ck(const float* __restrict__ X, __half* __restrict__ Xh, int n) {
  int i = blockIdx.x * blockDim.x + threadIdx.x;   // over n*32 float4 groups
  if (i >= n * 32) return;
  int r = i >> 5, q = i & 31;
  float4 v = ((const float4*)X)[i];
  int chunk = q >> 3;
  int fo = (q & 7) * 4;
  __half2* d = (__half2*)(Xh + (size_t)chunk * n * CF + (size_t)r * CF + fo);
  d[0] = __floats2half2_rn(v.x, v.y);
  d[1] = __floats2half2_rn(v.z, v.w);
}

// ---------------- chunked gather ----------------
// Quarter-wave (16 lanes) per row; lane owns 2 features (half2, 4B). 4 edge
// slots in flight per iteration, accumulated per-lane (no cross-lane reduce).
// pk loads are nontemporal (streamed x4/step; keep the hot chunk in L2).

__device__ __forceinline__ float2 gather_q(const int* __restrict__ rp,
                                           const long* __restrict__ pkl,
                                           const __half* __restrict__ Tc,
                                           int r, int l, int valid) {
  int e0 = 0, end = 0;
  if (valid) { e0 = rp[r]; end = rp[r + 1]; }
  float2 a0 = {0.f,0.f}, a1 = {0.f,0.f}, a2 = {0.f,0.f}, a3 = {0.f,0.f};
  for (int e = e0; e < end; e += 4) {
    long q0 = __builtin_nontemporal_load(pkl + e);       // pad-safe (32 zeros)
    long q1 = __builtin_nontemporal_load(pkl + e + 1);
    long q2 = __builtin_nontemporal_load(pkl + e + 2);
    long q3 = __builtin_nontemporal_load(pkl + e + 3);
    int c0 = (int)q0, c1 = (int)q1, c2 = (int)q2, c3 = (int)q3;
    float v0 = __int_as_float((int)(q0 >> 32));
    float v1 = (e + 1 < end) ? __int_as_float((int)(q1 >> 32)) : 0.f;
    float v2 = (e + 2 < end) ? __int_as_float((int)(q2 >> 32)) : 0.f;
    float v3 = (e + 3 < end) ? __int_as_float((int)(q3 >> 32)) : 0.f;
    float2 x0 = __half22float2(((const __half2*)(Tc + (size_t)c0 * CF))[l]);
    float2 x1 = __half22float2(((const __half2*)(Tc + (size_t)c1 * CF))[l]);
    float2 x2 = __half22float2(((const __half2*)(Tc + (size_t)c2 * CF))[l]);
    float2 x3 = __half22float2(((const __half2*)(Tc + (size_t)c3 * CF))[l]);
    a0.x = fmaf(v0, x0.x, a0.x); a0.y = fmaf(v0, x0.y, a0.y);
    a1.x = fmaf(v1, x1.x, a1.x); a1.y = fmaf(v1, x1.y, a1.y);
    a2.x = fmaf(v2, x2.x, a2.x); a2.y = fmaf(v2, x2.y, a2.y);
    a3.x = fmaf(v3, x3.x, a3.x); a3.y = fmaf(v3, x3.y, a3.y);
  }
  return make_float2((a0.x + a1.x) + (a2.x + a3.x), (a0.y + a1.y) + (a2.y + a3.y));
}

__device__ __forceinline__ __half2 ld_nt_h2(const __half* p) {
  unsigned u = __builtin_nontemporal_load((const unsigned*)p);
  return *(__half2*)&u;
}

// ---------------- Clenshaw steps (XCC-pinned chunks + work stealing) ----------------
// b_k = g2*(L @ src) - p + ck_eff * X ; all buffers chunked [4][n][32] fp16.

__global__ __launch_bounds__(BT) void clen_step_ck(
    const int* __restrict__ rp, const long* __restrict__ pkl,
    const __half* __restrict__ src, const __half* __restrict__ Xh, __half* pd,
    const float* __restrict__ coeffs, int k, int flags, int M, int n,
    int* __restrict__ ctr) {
  const int pref = xcc_id() >> 1;
  const int tid = threadIdx.x;
  const int warp = tid >> 6, qrow = (tid & 63) >> 4, l = tid & 15;
  const int nrb = (n + GRAB - 1) / GRAB;
  float ck = coeffs[k];
  if (flags & 2) ck -= coeffs[M - 1];
  const float g2 = (flags & 4) ? 2.f * coeffs[M - 1] : 2.f;
  __shared__ int srb;
  for (int cc = 0; cc < NCHUNK; ++cc) {
    const int chunk = (pref + cc) & (NCHUNK - 1);       // own chunk first, then steal
    const size_t coff = (size_t)chunk * n * CF;
    const __half* Tc = src + coff;
    while (true) {
      __syncthreads();
      if (tid == 0) srb = atomicAdd(&ctr[chunk], 1);
      __syncthreads();
      const int rb = srb;
      if (rb >= nrb) break;
      const int r = rb * GRAB + warp * 4 + qrow;
      const int valid = (r < n);
      float2 a = gather_q(rp, pkl, Tc, r, l, valid);
      if (valid) {
        const size_t off = coff + (size_t)r * CF;
        float2 x = __half22float2(ld_nt_h2(Xh + off) );
        float2 p = make_float2(0.f, 0.f);
        if (flags & 1) p = __half22float2(((const __half2*)(pd + off))[l]);
        // note: Xh lane index
        x = __half22float2(((const __half2*)(Xh + off))[l]);
        float2 t;
        t.x = fmaf(g2, a.x, fmaf(ck, x.x, -p.x));
        t.y = fmaf(g2, a.y, fmaf(ck, x.y, -p.y));
        ((__half2*)(pd + off))[l] = __floats2half2_rn(t.x, t.y);
      }
    }
  }
}

// out = c0*X + L @ b1 - b2   (fp32 X and output, [n][128] layout)
__global__ __launch_bounds__(BT) void clen_final_ck(
    const int* __restrict__ rp, const long* __restrict__ pkl,
    const __half* __restrict__ b1, const __half* __restrict__ b2,
    const float* __restrict__ X, float* __restrict__ out,
    const float* __restrict__ coeffs, int n, int* __restrict__ ctr) {
  const int pref = xcc_id() >> 1;
  const int tid = threadIdx.x;
  const int warp = tid >> 6, qrow = (tid & 63) >> 4, l = tid & 15;
  const int nrb = (n + GRAB - 1) / GRAB;
  const float c0 = coeffs[0];
  __shared__ int srb;
  for (int cc = 0; cc < NCHUNK; ++cc) {
    const int chunk = (pref + cc) & (NCHUNK - 1);
    const size_t coff = (size_t)chunk * n * CF;
    const __half* Tc = b1 + coff;
    while (true) {
      __syncthreads();
      if (tid == 0) srb = atomicAdd(&ctr[chunk], 1);
      __syncthreads();
      const int rb = srb;
      if (rb >= nrb) break;
      const int r = rb * GRAB + warp * 4 + qrow;
      const int valid = (r < n);
      float2 a = gather_q(rp, pkl, Tc, r, l, valid);
      if (valid) {
        const size_t off = coff + (size_t)r * CF;
        float2 p = __half22float2(((const __half2*)(b2 + off))[l]);
        const size_t xoff = (size_t)r * FD + chunk * CF + 2 * l;
        float2 x = *(const float2*)(X + xoff);
        float2 o;
        o.x = fmaf(c0, x.x, a.x - p.x);
        o.y = fmaf(c0, x.y, a.y - p.y);
        *(float2*)(out + xoff) = o;
      }
    }
  }
}

// ---------------- launch ----------------

extern "C" void kernel_launch(void* const* d_in, const int* in_sizes, int n_in,
                              void* d_out, int out_size, void* d_ws, size_t ws_size,
                              hipStream_t stream) {
  const int* rows = (const int*)d_in[0];
  const int* cols = (const int*)d_in[1];
  const float* vals = (const float*)d_in[2];
  const float* X = (const float*)d_in[3];
  const float* coeffs = (const float*)d_in[4];
  float* out = (float*)d_out;

  const int nnz = in_sizes[0];
  const int n = in_sizes[3] / FD;
  const int M = in_sizes[4];

  auto align_up = [](size_t x) { return (x + 255) & ~(size_t)255; };
  char* w = (char*)d_ws;
  size_t off = 0;
  int* row_ptr = (int*)(w + off); off = align_up(off + (size_t)(n + 1) * 4);
  int* row_fill = (int*)(w + off); off = align_up(off + (size_t)n * 4);
  int* bsum = (int*)(w + off); off = align_up(off + 1024 * 4);
  int* bpre = (int*)(w + off); off = align_up(off + 1024 * 4);
  int* ctrs = (int*)(w + off); off = align_up(off + 256 * 4);    // 4 per step dispatch
  int2* pk = (int2*)(w + off); off = align_up(off + ((size_t)nnz + 32) * 8);
  __half* Xh = (__half*)(w + off); off = align_up(off + (size_t)n * FD * 2);
  __half* buf0 = (__half*)(w + off); off = align_up(off + (size_t)n * FD * 2);
  __half* buf1 = (__half*)(w + off); off = align_up(off + (size_t)n * FD * 2);
  __half* bufs[2] = {buf0, buf1};
  (void)ws_size;

  const int B = 256;
  const int gN = (n + B - 1) / B;
  const int gE = (nnz + B - 1) / B;
  const int gC = (n * 32 + B - 1) / B;
  const long* pkl = (const long*)pk;

  // CSR build + counters
  zero_i32<<<gN, B, 0, stream>>>(row_fill, n);
  zero_i32<<<1, 256, 0, stream>>>(ctrs, 256);
  hist_kernel<<<gE, B, 0, stream>>>(rows, row_fill, nnz);
  block_reduce<<<gN, B, 0, stream>>>(row_fill, bsum, n);
  scan_bsum<<<1, 1024, 0, stream>>>(bsum, bpre, gN);
  block_scan<<<gN, B, 0, stream>>>(row_fill, bpre, row_ptr, n);
  copy_i32<<<gN, B, 0, stream>>>(row_ptr, row_fill, n);
  scatter_kernel<<<gE, B, 0, stream>>>(rows, cols, vals, row_fill, pk, nnz);
  f32_to_f16_ck<<<gC, B, 0, stream>>>(X, Xh, n);

  // Clenshaw (b_{M-1} = c_{M-1} X eliminated algebraically; M >= 4):
  // k = M-2: b = 2 c_{M-1} (L Xh) + c_{M-2} X            [flags = 4]
  // k = M-3: b = 2 (L b_{M-2}) + (c_{M-3} - c_{M-1}) X   [flags = 2]
  // k = M-4..1: b = 2 (L b_{k+1}) - b_{k+2} + c_k X      [flags = 1]
  // out = c0 X + L b1 - b2
  int si = 0;
  clen_step_ck<<<GRID_STEP, BT, 0, stream>>>(row_ptr, pkl, Xh, Xh, bufs[(M - 2) & 1],
                                             coeffs, M - 2, 4, M, n, ctrs + 4 * si);
  ++si;
  clen_step_ck<<<GRID_STEP, BT, 0, stream>>>(row_ptr, pkl, bufs[(M - 2) & 1], Xh,
                                             bufs[(M - 3) & 1], coeffs, M - 3, 2, M, n,
                                             ctrs + 4 * si);
  ++si;
  for (int k = M - 4; k >= 1; --k, ++si) {
    clen_step_ck<<<GRID_STEP, BT, 0, stream>>>(row_ptr, pkl, bufs[(k + 1) & 1], Xh,
                                               bufs[k & 1], coeffs, k, 1, M, n,
                                               ctrs + 4 * si);
  }
  clen_final_ck<<<GRID_STEP, BT, 0, stream>>>(row_ptr, pkl, bufs[1], bufs[0], X, out,
                                              coeffs, n, ctrs + 4 * si);
}

// Round 11
// 2637.539 us; speedup vs baseline: 2.7746x; 2.7746x over previous
//
#include <hip/hip_runtime.h>
#include <hip/hip_fp16.h>

#define FD 128          // feature dim
#define NCHUNK 4        // feature chunks; 32 feat x 2B x 50k rows = 3.2 MB (fits every XCD L2)
#define CF 32           // features per chunk
#define RPB 4           // rows per block (4 waves, 1 row each)
#define BT 256

typedef unsigned long long u64;

// ---------------- CSR build ----------------

__global__ void zero_i32(int* __restrict__ p, int n) {
  int i = blockIdx.x * blockDim.x + threadIdx.x;
  if (i < n) p[i] = 0;
}

__global__ void hist_kernel(const int* __restrict__ rows, int* __restrict__ cnt, int nnz) {
  int i = blockIdx.x * blockDim.x + threadIdx.x;
  if (i < nnz) atomicAdd(&cnt[rows[i]], 1);
}

__global__ void block_reduce(const int* __restrict__ cnt, int* __restrict__ bsum, int n) {
  __shared__ int sm[256];
  int i = blockIdx.x * 256 + threadIdx.x;
  sm[threadIdx.x] = (i < n) ? cnt[i] : 0;
  __syncthreads();
  for (int off = 128; off > 0; off >>= 1) {
    if (threadIdx.x < off) sm[threadIdx.x] += sm[threadIdx.x + off];
    __syncthreads();
  }
  if (threadIdx.x == 0) bsum[blockIdx.x] = sm[0];
}

__global__ void scan_bsum(const int* __restrict__ bsum, int* __restrict__ bpre, int nb) {
  __shared__ int sm[1024];
  const int tid = threadIdx.x;
  sm[tid] = (tid < nb) ? bsum[tid] : 0;
  __syncthreads();
  for (int off = 1; off < 1024; off <<= 1) {
    int t = (tid >= off) ? sm[tid - off] : 0;
    __syncthreads();
    sm[tid] += t;
    __syncthreads();
  }
  if (tid < nb) bpre[tid] = (tid == 0) ? 0 : sm[tid - 1];
}

__global__ void block_scan(const int* __restrict__ cnt, const int* __restrict__ bpre,
                           int* __restrict__ row_ptr, int n) {
  __shared__ int sm[256];
  const int tid = threadIdx.x;
  int i = blockIdx.x * 256 + tid;
  sm[tid] = (i < n) ? cnt[i] : 0;
  __syncthreads();
  for (int off = 1; off < 256; off <<= 1) {
    int t = (tid >= off) ? sm[tid - off] : 0;
    __syncthreads();
    sm[tid] += t;
    __syncthreads();
  }
  if (i < n) row_ptr[i + 1] = sm[tid] + bpre[blockIdx.x];
  if (i == 0) row_ptr[0] = 0;
}

__global__ void copy_i32(const int* __restrict__ src, int* __restrict__ dst, int n) {
  int i = blockIdx.x * blockDim.x + threadIdx.x;
  if (i < n) dst[i] = src[i];
}

// packed edge scatter: one 8B store per edge + 32-entry zero pad
__global__ void scatter_kernel(const int* __restrict__ rows, const int* __restrict__ cols,
                               const float* __restrict__ vals, int* __restrict__ fill,
                               int2* __restrict__ pk, int nnz) {
  int i = blockIdx.x * blockDim.x + threadIdx.x;
  if (i < 32) pk[nnz + i] = make_int2(0, 0);
  if (i < nnz) {
    int r = rows[i];
    int pos = atomicAdd(&fill[r], 1);
    pk[pos] = make_int2(cols[i], __float_as_int(vals[i]));
  }
}

// X (f32, [n][128]) -> Xh chunked (f16, [4][n][32])
__global__ void f32_to_f16_ck(const float* __restrict__ X, __half* __restrict__ Xh, int n) {
  int i = blockIdx.x * blockDim.x + threadIdx.x;   // over n*32 float4 groups
  if (i >= n * 32) return;
  int r = i >> 5, q = i & 31;
  float4 v = ((const float4*)X)[i];
  int chunk = q >> 3;
  int fo = (q & 7) * 4;
  __half2* d = (__half2*)(Xh + (size_t)chunk * n * CF + (size_t)r * CF + fo);
  d[0] = __floats2half2_rn(v.x, v.y);
  d[1] = __floats2half2_rn(v.z, v.w);
}

// ---------------- helpers: 8B as u64 with half-precision unpack ----------------

__device__ __forceinline__ float2 lo_h2f(u64 q) {
  unsigned u = (unsigned)q;
  return __half22float2(*(__half2*)&u);
}
__device__ __forceinline__ float2 hi_h2f(u64 q) {
  unsigned u = (unsigned)(q >> 32);
  return __half22float2(*(__half2*)&u);
}
__device__ __forceinline__ u64 pack_h4(float a, float b, float c, float d) {
  __half2 l = __floats2half2_rn(a, b);
  __half2 h = __floats2half2_rn(c, d);
  return (u64)(*(unsigned*)&l) | ((u64)(*(unsigned*)&h) << 32);
}

// ---------------- chunked gather ----------------
// Full wave per row. sub = lane>>3 picks 1 of 8 edges per round; fl = lane&7
// picks a 4-feature 8B group -> 8 lanes cover one 64B chunk-row, 8 edges in
// flight per round. Degree-16 row = 2 rounds, depth-2 dependent chain.
// pk loads nontemporal (streamed; keep hot chunk in L2).

struct F4 { float a0, a1, a2, a3; };

__device__ __forceinline__ void fma_cv(u64 q, float v, const __half* __restrict__ Tc,
                                       int fl, F4& acc) {
  int c = (int)(unsigned)q;
  u64 raw = *(const u64*)(Tc + (size_t)c * CF + 4 * fl);
  float2 x0 = lo_h2f(raw), x1 = hi_h2f(raw);
  acc.a0 = fmaf(v, x0.x, acc.a0);
  acc.a1 = fmaf(v, x0.y, acc.a1);
  acc.a2 = fmaf(v, x1.x, acc.a2);
  acc.a3 = fmaf(v, x1.y, acc.a3);
}

__device__ __forceinline__ F4 gather8(const int* __restrict__ rp,
                                      const u64* __restrict__ pkl,
                                      const __half* __restrict__ Tc,
                                      int r, int sub, int fl) {
  const int e0 = rp[r];
  const int d = rp[r + 1] - e0;
  const int trips = (d + 7) >> 3;
  F4 acc = {0.f, 0.f, 0.f, 0.f};
  int j = 0;
  for (; j + 2 <= trips; j += 2) {
    int i0 = e0 + 8 * j + sub;
    u64 q0 = __builtin_nontemporal_load(pkl + i0);       // pad-safe
    u64 q1 = __builtin_nontemporal_load(pkl + i0 + 8);
    float v0 = (8 * j + sub < d) ? __int_as_float((int)(q0 >> 32)) : 0.f;
    float v1 = (8 * j + 8 + sub < d) ? __int_as_float((int)(q1 >> 32)) : 0.f;
    fma_cv(q0, v0, Tc, fl, acc);
    fma_cv(q1, v1, Tc, fl, acc);
  }
  if (j < trips) {
    int i0 = e0 + 8 * j + sub;
    u64 q0 = __builtin_nontemporal_load(pkl + i0);
    float v0 = (8 * j + sub < d) ? __int_as_float((int)(q0 >> 32)) : 0.f;
    fma_cv(q0, v0, Tc, fl, acc);
  }
  // reduce across the 8 subs (3 shfl rounds)
#pragma unroll
  for (int m = 8; m < 64; m <<= 1) {
    acc.a0 += __shfl_xor(acc.a0, m, 64);
    acc.a1 += __shfl_xor(acc.a1, m, 64);
    acc.a2 += __shfl_xor(acc.a2, m, 64);
    acc.a3 += __shfl_xor(acc.a3, m, 64);
  }
  return acc;
}

// ---------------- Clenshaw steps (phase-coherent chunk sweep) ----------------
// chunk = blockIdx / bpc: the resident-block window sweeps one chunk at a time,
// so each 3.2 MB read-only source chunk is L2-resident on EVERY XCD (read
// replication, no pinning assumption). All b buffers chunked [4][n][32] fp16.
// b_k = g2*(L @ src) - p + ck_eff * X

__global__ __launch_bounds__(BT) void clen_step_ck(
    const int* __restrict__ rp, const u64* __restrict__ pkl,
    const __half* __restrict__ src, const __half* __restrict__ Xh, __half* pd,
    const float* __restrict__ coeffs, int k, int flags, int M, int n, int bpc) {
  const int chunk = blockIdx.x / bpc;
  const int rb = blockIdx.x - chunk * bpc;
  const int lane = threadIdx.x & 63;
  const int sub = lane >> 3, fl = lane & 7;
  const int r = rb * RPB + (threadIdx.x >> 6);
  if (r >= n) return;
  const size_t coff = (size_t)chunk * n * CF;
  F4 a = gather8(rp, pkl, src + coff, r, sub, fl);
  if (sub == 0) {
    float ck = coeffs[k];
    if (flags & 2) ck -= coeffs[M - 1];
    const float g2 = (flags & 4) ? 2.f * coeffs[M - 1] : 2.f;
    const size_t off = coff + (size_t)r * CF + 4 * fl;
    u64 xr = __builtin_nontemporal_load((const u64*)(Xh + off));
    float2 x0 = lo_h2f(xr), x1 = hi_h2f(xr);
    float2 p0 = {0.f, 0.f}, p1 = {0.f, 0.f};
    if (flags & 1) {
      u64 pr = __builtin_nontemporal_load((const u64*)(pd + off));
      p0 = lo_h2f(pr); p1 = hi_h2f(pr);
    }
    float t0 = fmaf(g2, a.a0, fmaf(ck, x0.x, -p0.x));
    float t1 = fmaf(g2, a.a1, fmaf(ck, x0.y, -p0.y));
    float t2 = fmaf(g2, a.a2, fmaf(ck, x1.x, -p1.x));
    float t3 = fmaf(g2, a.a3, fmaf(ck, x1.y, -p1.y));
    __builtin_nontemporal_store(pack_h4(t0, t1, t2, t3), (u64*)(pd + off));
  }
}

// out = c0*X + L @ b1 - b2   (fp32 X and output, [n][128] layout)
__global__ __launch_bounds__(BT) void clen_final_ck(
    const int* __restrict__ rp, const u64* __restrict__ pkl,
    const __half* __restrict__ b1, const __half* __restrict__ b2,
    const float* __restrict__ X, float* __restrict__ out,
    const float* __restrict__ coeffs, int n, int bpc) {
  const int chunk = blockIdx.x / bpc;
  const int rb = blockIdx.x - chunk * bpc;
  const int lane = threadIdx.x & 63;
  const int sub = lane >> 3, fl = lane & 7;
  const int r = rb * RPB + (threadIdx.x >> 6);
  if (r >= n) return;
  const size_t coff = (size_t)chunk * n * CF;
  F4 a = gather8(rp, pkl, b1 + coff, r, sub, fl);
  if (sub == 0) {
    const float c0 = coeffs[0];
    const size_t off = coff + (size_t)r * CF + 4 * fl;
    u64 pr = __builtin_nontemporal_load((const u64*)(b2 + off));
    float2 p0 = lo_h2f(pr), p1 = hi_h2f(pr);
    const size_t xoff = (size_t)r * FD + chunk * CF + 4 * fl;
    float4 x = *(const float4*)(X + xoff);
    float4 o;
    o.x = fmaf(c0, x.x, a.a0 - p0.x);
    o.y = fmaf(c0, x.y, a.a1 - p0.y);
    o.z = fmaf(c0, x.z, a.a2 - p1.x);
    o.w = fmaf(c0, x.w, a.a3 - p1.y);
    *(float4*)(out + xoff) = o;
  }
}

// ---------------- launch ----------------

extern "C" void kernel_launch(void* const* d_in, const int* in_sizes, int n_in,
                              void* d_out, int out_size, void* d_ws, size_t ws_size,
                              hipStream_t stream) {
  const int* rows = (const int*)d_in[0];
  const int* cols = (const int*)d_in[1];
  const float* vals = (const float*)d_in[2];
  const float* X = (const float*)d_in[3];
  const float* coeffs = (const float*)d_in[4];
  float* out = (float*)d_out;

  const int nnz = in_sizes[0];
  const int n = in_sizes[3] / FD;
  const int M = in_sizes[4];

  auto align_up = [](size_t x) { return (x + 255) & ~(size_t)255; };
  char* w = (char*)d_ws;
  size_t off = 0;
  int* row_ptr = (int*)(w + off); off = align_up(off + (size_t)(n + 1) * 4);
  int* row_fill = (int*)(w + off); off = align_up(off + (size_t)n * 4);
  int* bsum = (int*)(w + off); off = align_up(off + 1024 * 4);
  int* bpre = (int*)(w + off); off = align_up(off + 1024 * 4);
  int2* pk = (int2*)(w + off); off = align_up(off + ((size_t)nnz + 32) * 8);
  __half* Xh = (__half*)(w + off); off = align_up(off + (size_t)n * FD * 2);
  __half* buf0 = (__half*)(w + off); off = align_up(off + (size_t)n * FD * 2);
  __half* buf1 = (__half*)(w + off); off = align_up(off + (size_t)n * FD * 2);
  __half* bufs[2] = {buf0, buf1};
  (void)ws_size;

  const int B = 256;
  const int gN = (n + B - 1) / B;
  const int gE = (nnz + B - 1) / B;
  const int gC = (n * 32 + B - 1) / B;
  const int bpc = (n + RPB - 1) / RPB;      // blocks per chunk
  const int gS = NCHUNK * bpc;
  const u64* pkl = (const u64*)pk;

  // CSR build
  zero_i32<<<gN, B, 0, stream>>>(row_fill, n);
  hist_kernel<<<gE, B, 0, stream>>>(rows, row_fill, nnz);
  block_reduce<<<gN, B, 0, stream>>>(row_fill, bsum, n);
  scan_bsum<<<1, 1024, 0, stream>>>(bsum, bpre, gN);
  block_scan<<<gN, B, 0, stream>>>(row_fill, bpre, row_ptr, n);
  copy_i32<<<gN, B, 0, stream>>>(row_ptr, row_fill, n);
  scatter_kernel<<<gE, B, 0, stream>>>(rows, cols, vals, row_fill, pk, nnz);
  f32_to_f16_ck<<<gC, B, 0, stream>>>(X, Xh, n);

  // Clenshaw (b_{M-1} = c_{M-1} X eliminated algebraically; M >= 4):
  // k = M-2: b = 2 c_{M-1} (L Xh) + c_{M-2} X            [flags = 4]
  // k = M-3: b = 2 (L b_{M-2}) + (c_{M-3} - c_{M-1}) X   [flags = 2]
  // k = M-4..1: b = 2 (L b_{k+1}) - b_{k+2} + c_k X      [flags = 1]
  // out = c0 X + L b1 - b2
  clen_step_ck<<<gS, BT, 0, stream>>>(row_ptr, pkl, Xh, Xh, bufs[(M - 2) & 1],
                                      coeffs, M - 2, 4, M, n, bpc);
  clen_step_ck<<<gS, BT, 0, stream>>>(row_ptr, pkl, bufs[(M - 2) & 1], Xh,
                                      bufs[(M - 3) & 1], coeffs, M - 3, 2, M, n, bpc);
  for (int k = M - 4; k >= 1; --k) {
    clen_step_ck<<<gS, BT, 0, stream>>>(row_ptr, pkl, bufs[(k + 1) & 1], Xh,
                                        bufs[k & 1], coeffs, k, 1, M, n, bpc);
  }
  clen_final_ck<<<gS, BT, 0, stream>>>(row_ptr, pkl, bufs[1], bufs[0], X, out,
                                       coeffs, n, bpc);
}

// Round 12
// 1145.631 us; speedup vs baseline: 6.3879x; 2.3023x over previous
//
#include <hip/hip_runtime.h>
#include <hip/hip_fp16.h>

#define FD 128          // feature dim
#define RPB 4           // rows (waves) per block; block = 256 threads
// NOTE: algebraic elimination of b_{M-1} assumes M >= 4 (here M = 30).

// ---------------- CSR build ----------------

__global__ void zero_i32(int* __restrict__ p, int n) {
  int i = blockIdx.x * blockDim.x + threadIdx.x;
  if (i < n) p[i] = 0;
}

__global__ void hist_kernel(const int* __restrict__ rows, int* __restrict__ cnt, int nnz) {
  int i = blockIdx.x * blockDim.x + threadIdx.x;
  if (i < nnz) atomicAdd(&cnt[rows[i]], 1);
}

// coalesced 3-phase scan
__global__ void block_reduce(const int* __restrict__ cnt, int* __restrict__ bsum, int n) {
  __shared__ int sm[256];
  int i = blockIdx.x * 256 + threadIdx.x;
  sm[threadIdx.x] = (i < n) ? cnt[i] : 0;
  __syncthreads();
  for (int off = 128; off > 0; off >>= 1) {
    if (threadIdx.x < off) sm[threadIdx.x] += sm[threadIdx.x + off];
    __syncthreads();
  }
  if (threadIdx.x == 0) bsum[blockIdx.x] = sm[0];
}

__global__ void scan_bsum(const int* __restrict__ bsum, int* __restrict__ bpre, int nb) {
  __shared__ int sm[1024];
  const int tid = threadIdx.x;
  sm[tid] = (tid < nb) ? bsum[tid] : 0;
  __syncthreads();
  for (int off = 1; off < 1024; off <<= 1) {
    int t = (tid >= off) ? sm[tid - off] : 0;
    __syncthreads();
    sm[tid] += t;
    __syncthreads();
  }
  if (tid < nb) bpre[tid] = (tid == 0) ? 0 : sm[tid - 1];
}

__global__ void block_scan(const int* __restrict__ cnt, const int* __restrict__ bpre,
                           int* __restrict__ row_ptr, int n) {
  __shared__ int sm[256];
  const int tid = threadIdx.x;
  int i = blockIdx.x * 256 + tid;
  sm[tid] = (i < n) ? cnt[i] : 0;
  __syncthreads();
  for (int off = 1; off < 256; off <<= 1) {
    int t = (tid >= off) ? sm[tid - off] : 0;
    __syncthreads();
    sm[tid] += t;
    __syncthreads();
  }
  if (i < n) row_ptr[i + 1] = sm[tid] + bpre[blockIdx.x];
  if (i == 0) row_ptr[0] = 0;
}

__global__ void copy_i32(const int* __restrict__ src, int* __restrict__ dst, int n) {
  int i = blockIdx.x * blockDim.x + threadIdx.x;
  if (i < n) dst[i] = src[i];
}

// packed edge scatter: one 8B store per edge (at the write-allocate floor)
__global__ void scatter_kernel(const int* __restrict__ rows, const int* __restrict__ cols,
                               const float* __restrict__ vals, int* __restrict__ fill,
                               int2* __restrict__ pk, int nnz) {
  int i = blockIdx.x * blockDim.x + threadIdx.x;
  if (i < nnz) {
    int r = rows[i];
    int pos = atomicAdd(&fill[r], 1);
    pk[pos] = make_int2(cols[i], __float_as_int(vals[i]));
  }
}

__global__ void f32_to_f16(const float* __restrict__ src, __half* __restrict__ dst, int n4) {
  int i = blockIdx.x * blockDim.x + threadIdx.x;
  if (i < n4) {
    float4 v = ((const float4*)src)[i];
    __half2* d = (__half2*)dst + 2 * (size_t)i;
    d[0] = __floats2half2_rn(v.x, v.y);
    d[1] = __floats2half2_rn(v.z, v.w);
  }
}

// ---------------- wide gather (R7-proven shape) ----------------
// Wave = 1 row. sub = lane>>4 picks 1 of 4 edges; fl = lane&15 picks an 8-feature
// quad (uint4 = 16B). One load instruction covers 4 edges x 256B = 1024B.

__device__ __forceinline__ void fma_edge(const __half* __restrict__ T, int c, float v,
                                         int fl, float2 acc[4]) {
  uint4 raw = ((const uint4*)(T + (size_t)c * FD))[fl];
  const __half2* h = (const __half2*)&raw;
  float2 x0 = __half22float2(h[0]);
  float2 x1 = __half22float2(h[1]);
  float2 x2 = __half22float2(h[2]);
  float2 x3 = __half22float2(h[3]);
  acc[0].x = fmaf(v, x0.x, acc[0].x); acc[0].y = fmaf(v, x0.y, acc[0].y);
  acc[1].x = fmaf(v, x1.x, acc[1].x); acc[1].y = fmaf(v, x1.y, acc[1].y);
  acc[2].x = fmaf(v, x2.x, acc[2].x); acc[2].y = fmaf(v, x2.y, acc[2].y);
  acc[3].x = fmaf(v, x3.x, acc[3].x); acc[3].y = fmaf(v, x3.y, acc[3].y);
}

__device__ __forceinline__ void gather_row(const int* __restrict__ rp,
                                           const int2* __restrict__ pk,
                                           const __half* __restrict__ T,
                                           int r, int sub, int fl, float2 acc[4]) {
  int e = rp[r];
  const int end = rp[r + 1];
  for (; e + 8 <= end; e += 8) {
    int2 cv0 = pk[e + sub];
    int2 cv1 = pk[e + 4 + sub];
    fma_edge(T, cv0.x, __int_as_float(cv0.y), fl, acc);
    fma_edge(T, cv1.x, __int_as_float(cv1.y), fl, acc);
  }
  if (e + 4 <= end) {
    int2 cv = pk[e + sub];
    fma_edge(T, cv.x, __int_as_float(cv.y), fl, acc);
    e += 4;
  }
  if (e < end) {
    int idx = e + sub;
    int2 cv = pk[min(idx, end - 1)];
    float v = (idx < end) ? __int_as_float(cv.y) : 0.f;
    fma_edge(T, cv.x, v, fl, acc);
  }
}

__device__ __forceinline__ void reduce_subs(float2 acc[4]) {
#pragma unroll
  for (int m = 16; m < 64; m <<= 1) {
#pragma unroll
    for (int q = 0; q < 4; ++q) {
      acc[q].x += __shfl_xor(acc[q].x, m, 64);
      acc[q].y += __shfl_xor(acc[q].y, m, 64);
    }
  }
}

// ---------------- Clenshaw steps ----------------
// b_k = g2*(L @ src) - p + ck_eff * X   (fp16 state, fp32 math)
// flags: bit0 = read p from pd; bit1 = ck_eff = c_k - c_{M-1} (folds b_{M-1});
//        bit2 = g2 = 2*c_{M-1} (src is Xh standing in for b_{M-1} = c_{M-1} X).
// pd holds b_{k+2} and receives b_k (same element, same lane -> safe in-place).

__global__ __launch_bounds__(256) void clen_step(
    const int* __restrict__ rp, const int2* __restrict__ pk,
    const __half* __restrict__ src, const __half* __restrict__ Xh, __half* pd,
    const float* __restrict__ coeffs, int k, int flags, int M, int n) {
  const int lane = threadIdx.x & 63;
  const int sub = lane >> 4, fl = lane & 15;
  const int r = blockIdx.x * RPB + (threadIdx.x >> 6);
  if (r >= n) return;
  float2 acc[4] = {{0.f,0.f},{0.f,0.f},{0.f,0.f},{0.f,0.f}};
  gather_row(rp, pk, src, r, sub, fl, acc);
  reduce_subs(acc);
  if (sub == 0) {
    float ck = coeffs[k];
    if (flags & 2) ck -= coeffs[M - 1];
    const float g2 = (flags & 4) ? 2.f * coeffs[M - 1] : 2.f;
    uint4 xr = ((const uint4*)(Xh + (size_t)r * FD))[fl];
    const __half2* xh = (const __half2*)&xr;
    float2 p[4] = {{0.f,0.f},{0.f,0.f},{0.f,0.f},{0.f,0.f}};
    if (flags & 1) {
      uint4 pr = ((const uint4*)(pd + (size_t)r * FD))[fl];
      const __half2* ph = (const __half2*)&pr;
#pragma unroll
      for (int q = 0; q < 4; ++q) p[q] = __half22float2(ph[q]);
    }
    uint4 orr;
    __half2* oh = (__half2*)&orr;
#pragma unroll
    for (int q = 0; q < 4; ++q) {
      float2 x = __half22float2(xh[q]);
      float tx = fmaf(g2, acc[q].x, fmaf(ck, x.x, -p[q].x));
      float ty = fmaf(g2, acc[q].y, fmaf(ck, x.y, -p[q].y));
      oh[q] = __floats2half2_rn(tx, ty);
    }
    ((uint4*)(pd + (size_t)r * FD))[fl] = orr;
  }
}

// out = c0*X + L @ b1 - b2   (fp32 X and output)
__global__ __launch_bounds__(256) void clen_final(
    const int* __restrict__ rp, const int2* __restrict__ pk,
    const __half* __restrict__ b1, const __half* __restrict__ b2,
    const float* __restrict__ X, float* __restrict__ out,
    const float* __restrict__ coeffs, int n) {
  const int lane = threadIdx.x & 63;
  const int sub = lane >> 4, fl = lane & 15;
  const int r = blockIdx.x * RPB + (threadIdx.x >> 6);
  if (r >= n) return;
  float2 acc[4] = {{0.f,0.f},{0.f,0.f},{0.f,0.f},{0.f,0.f}};
  gather_row(rp, pk, b1, r, sub, fl, acc);
  reduce_subs(acc);
  if (sub == 0) {
    const float c0 = coeffs[0];
    uint4 pr = ((const uint4*)(b2 + (size_t)r * FD))[fl];
    const __half2* ph = (const __half2*)&pr;
    float4 x0 = ((const float4*)(X + (size_t)r * FD))[fl * 2];
    float4 x1 = ((const float4*)(X + (size_t)r * FD))[fl * 2 + 1];
    float2 p0 = __half22float2(ph[0]), p1 = __half22float2(ph[1]);
    float2 p2 = __half22float2(ph[2]), p3 = __half22float2(ph[3]);
    float4 o0, o1;
    o0.x = fmaf(c0, x0.x, acc[0].x - p0.x);
    o0.y = fmaf(c0, x0.y, acc[0].y - p0.y);
    o0.z = fmaf(c0, x0.z, acc[1].x - p1.x);
    o0.w = fmaf(c0, x0.w, acc[1].y - p1.y);
    o1.x = fmaf(c0, x1.x, acc[2].x - p2.x);
    o1.y = fmaf(c0, x1.y, acc[2].y - p2.y);
    o1.z = fmaf(c0, x1.z, acc[3].x - p3.x);
    o1.w = fmaf(c0, x1.w, acc[3].y - p3.y);
    ((float4*)(out + (size_t)r * FD))[fl * 2] = o0;
    ((float4*)(out + (size_t)r * FD))[fl * 2 + 1] = o1;
  }
}

// ---------------- launch ----------------

extern "C" void kernel_launch(void* const* d_in, const int* in_sizes, int n_in,
                              void* d_out, int out_size, void* d_ws, size_t ws_size,
                              hipStream_t stream) {
  const int* rows = (const int*)d_in[0];
  const int* cols = (const int*)d_in[1];
  const float* vals = (const float*)d_in[2];
  const float* X = (const float*)d_in[3];
  const float* coeffs = (const float*)d_in[4];
  float* out = (float*)d_out;

  const int nnz = in_sizes[0];
  const int n = in_sizes[3] / FD;
  const int M = in_sizes[4];

  auto align_up = [](size_t x) { return (x + 255) & ~(size_t)255; };
  char* w = (char*)d_ws;
  size_t off = 0;
  int* row_ptr = (int*)(w + off); off = align_up(off + (size_t)(n + 1) * 4);
  int* row_fill = (int*)(w + off); off = align_up(off + (size_t)n * 4);
  int* bsum = (int*)(w + off); off = align_up(off + 1024 * 4);
  int* bpre = (int*)(w + off); off = align_up(off + 1024 * 4);
  int2* pk = (int2*)(w + off); off = align_up(off + (size_t)nnz * 8);
  __half* Xh = (__half*)(w + off); off = align_up(off + (size_t)n * FD * 2);
  __half* buf0 = (__half*)(w + off); off = align_up(off + (size_t)n * FD * 2);
  __half* buf1 = (__half*)(w + off); off = align_up(off + (size_t)n * FD * 2);
  __half* bufs[2] = {buf0, buf1};
  (void)ws_size;

  const int B = 256;
  const int gN = (n + B - 1) / B;
  const int gE = (nnz + B - 1) / B;
  const int gS = (n + RPB - 1) / RPB;
  const int n4 = n * FD / 4;
  const int gC = (n4 + B - 1) / B;

  // CSR build
  zero_i32<<<gN, B, 0, stream>>>(row_fill, n);
  hist_kernel<<<gE, B, 0, stream>>>(rows, row_fill, nnz);
  block_reduce<<<gN, B, 0, stream>>>(row_fill, bsum, n);
  scan_bsum<<<1, 1024, 0, stream>>>(bsum, bpre, gN);
  block_scan<<<gN, B, 0, stream>>>(row_fill, bpre, row_ptr, n);
  copy_i32<<<gN, B, 0, stream>>>(row_ptr, row_fill, n);
  scatter_kernel<<<gE, B, 0, stream>>>(rows, cols, vals, row_fill, pk, nnz);
  f32_to_f16<<<gC, B, 0, stream>>>(X, Xh, n4);

  // Clenshaw (b_{M-1} = c_{M-1} X eliminated algebraically; M >= 4):
  // k = M-2: b = 2 c_{M-1} (L Xh) + c_{M-2} X            [flags = 4]
  // k = M-3: b = 2 (L b_{M-2}) + (c_{M-3} - c_{M-1}) X   [flags = 2]
  // k = M-4..1: b = 2 (L b_{k+1}) - b_{k+2} + c_k X      [flags = 1]
  // out = c0 X + L b1 - b2
  clen_step<<<gS, B, 0, stream>>>(row_ptr, pk, Xh, Xh, bufs[(M - 2) & 1],
                                  coeffs, M - 2, 4, M, n);
  clen_step<<<gS, B, 0, stream>>>(row_ptr, pk, bufs[(M - 2) & 1], Xh, bufs[(M - 3) & 1],
                                  coeffs, M - 3, 2, M, n);
  for (int k = M - 4; k >= 1; --k) {
    clen_step<<<gS, B, 0, stream>>>(row_ptr, pk, bufs[(k + 1) & 1], Xh, bufs[k & 1],
                                    coeffs, k, 1, M, n);
  }
  clen_final<<<gS, B, 0, stream>>>(row_ptr, pk, bufs[1], bufs[0], X, out, coeffs, n);
}